// Round 7
// baseline (152.770 us; speedup 1.0000x reference)
//
#include <hip/hip_runtime.h>
#include <math.h>

// Problem constants (reference: B=2048, CI=32, CO=32, A=16, ITER_NUM=5)
constexpr int CI = 32;
constexpr int CO = 32;
constexpr float INV_N   = 1.0f / 65536.0f;
constexpr float INV_NM1 = 1.0f / 65535.0f;

constexpr int NCHUNK = 32;                 // chunks per capsule (grid = 32*32)
constexpr int PART_STRIDE = 272;           // 4 subs * 68 (64 prods + 4 sums)

// d_ws float layout (no zero-init required):
//   WS_PART: [CI][NCHUNK][272] per-block partials
//   WS_WG:   [CI][16][16]  folded W*gamma
//   WS_C0:   [CI][16]      folded bias: beta - (mean @ W)*gamma
constexpr int WS_PART = 0;
constexpr int WS_WG   = CI * NCHUNK * PART_STRIDE;   // 278528
constexpr int WS_C0   = WS_WG + CI * 256;

using f32x4 = __attribute__((ext_vector_type(4))) float;

// ---------------------------------------------------------------------------
// Kernel 1: per-capsule raw sums S[a] = sum x_a, P[a][b] = sum x_a x_b.
// Grid: 32 ci * 32 chunks = 1024 blocks of 256 threads, 4 blocks/CU.
// Quad of lanes shares one 16-float vector (4 float4 loads, L1-dedup'd);
// lane (tid&3) accumulates its 4 rows x 16 cols slab in registers.
// PREFETCH DEPTH 1: iteration it+1's loads issue before it's 68 FMAs, so
// ~500cy HBM latency hides under compute x 4 resident waves/SIMD.
// ---------------------------------------------------------------------------
__global__ __launch_bounds__(256) void k_stats(const float* __restrict__ x,
                                               float* __restrict__ ws) {
    const int ci    = blockIdx.x & 31;
    const int chunk = blockIdx.x >> 5;          // 0..31
    const int tid   = threadIdx.x;
    const int sub   = tid & 3;                  // row-group selector
    const int quad  = tid >> 2;                 // 0..63 vector slot in block

    float acc[4][16];
    float sacc[4];
#pragma unroll
    for (int i = 0; i < 4; ++i) {
        sacc[i] = 0.0f;
#pragma unroll
        for (int b2 = 0; b2 < 16; ++b2) acc[i][b2] = 0.0f;
    }

    // n = chunk*2048 + it*64 + quad; b = n>>5, co = n&31. As it++ -> b += 2,
    // co fixed => pointer advances by a CONSTANT 2*32*32*16 = 32768 floats.
    const float* p = x +
        (((size_t)(chunk * 64 + (quad >> 5)) * 32 + ci) * 32 + (quad & 31)) * 16;

    auto body = [&](const float4& f0, const float4& f1,
                    const float4& f2, const float4& f3) {
        const float v[16] = {f0.x, f0.y, f0.z, f0.w,  f1.x, f1.y, f1.z, f1.w,
                             f2.x, f2.y, f2.z, f2.w,  f3.x, f3.y, f3.z, f3.w};
        // lane's own quarter = register select (replaces a redundant 5th load)
        const float4 fo = (sub == 0) ? f0 : (sub == 1) ? f1 : (sub == 2) ? f2 : f3;
        const float ow[4] = {fo.x, fo.y, fo.z, fo.w};
#pragma unroll
        for (int i = 0; i < 4; ++i) {
            sacc[i] += ow[i];
#pragma unroll
            for (int b2 = 0; b2 < 16; ++b2) acc[i][b2] += ow[i] * v[b2];
        }
    };

    float4 f0 = *reinterpret_cast<const float4*>(p);
    float4 f1 = *reinterpret_cast<const float4*>(p + 4);
    float4 f2 = *reinterpret_cast<const float4*>(p + 8);
    float4 f3 = *reinterpret_cast<const float4*>(p + 12);

    for (int it = 0; it < 31; ++it) {
        const float* pn = p + 32768;
        const float4 g0 = *reinterpret_cast<const float4*>(pn);
        const float4 g1 = *reinterpret_cast<const float4*>(pn + 4);
        const float4 g2 = *reinterpret_cast<const float4*>(pn + 8);
        const float4 g3 = *reinterpret_cast<const float4*>(pn + 12);

        body(f0, f1, f2, f3);

        f0 = g0; f1 = g1; f2 = g2; f3 = g3;
        p = pn;
    }
    body(f0, f1, f2, f3);                       // peeled last iteration

    // Butterfly-reduce across the 16 quads of the wave (lanes with same sub).
#pragma unroll
    for (int m = 4; m < 64; m <<= 1) {
#pragma unroll
        for (int i = 0; i < 4; ++i) {
            sacc[i] += __shfl_xor(sacc[i], m, 64);
#pragma unroll
            for (int b2 = 0; b2 < 16; ++b2)
                acc[i][b2] += __shfl_xor(acc[i][b2], m, 64);
        }
    }

    // Cross-wave reduce in LDS: lanes 0..3 of each wave hold wave totals.
    __shared__ float red[4][272];
    const int wv = tid >> 6;
    if ((tid & 63) < 4) {
#pragma unroll
        for (int i = 0; i < 4; ++i) {
#pragma unroll
            for (int b2 = 0; b2 < 16; ++b2)
                red[wv][sub * 68 + i * 16 + b2] = acc[i][b2];
            red[wv][sub * 68 + 64 + i] = sacc[i];
        }
    }
    __syncthreads();
    float* slot = ws + WS_PART + (ci * NCHUNK + chunk) * PART_STRIDE;
    for (int e = tid; e < 272; e += 256) {
        slot[e] = red[0][e] + red[1][e] + red[2][e] + red[3][e];
    }
}

// ---------------------------------------------------------------------------
// Kernel 2: reduce chunk partials, Newton-Schulz inverse sqrt, then FOLD the
// epilogue constants: WG = W*gamma (per column), C0 = beta - (mean@W)*gamma.
// 32 blocks (one per ci) of 256 threads.
// ---------------------------------------------------------------------------
__global__ __launch_bounds__(256) void k_ns(const float* __restrict__ gamma,
                                            const float* __restrict__ beta,
                                            float* __restrict__ ws) {
    const int ci  = blockIdx.x;
    const int tid = threadIdx.x;
    const int r = tid >> 4, c = tid & 15;

    __shared__ float red2[272];
    __shared__ float sig[16][17];
    __shared__ float pm[16][17];
    __shared__ float t1[16][17];
    __shared__ float t2[16][17];
    __shared__ float trace_s;

    const float* base = ws + WS_PART + (size_t)ci * NCHUNK * PART_STRIDE;
    for (int e = tid; e < 272; e += 256) {
        float s = 0.0f;
#pragma unroll
        for (int ch = 0; ch < NCHUNK; ++ch)
            s += base[ch * PART_STRIDE + e];
        red2[e] = s;
    }
    __syncthreads();

    // sigma[r][c] = (P_rc - S_r*S_c/N) / (N-1)
    const float P_rc = red2[(r >> 2) * 68 + ((r & 3) << 4) + c];
    const float S_r  = red2[(r >> 2) * 68 + 64 + (r & 3)];
    const float S_c  = red2[(c >> 2) * 68 + 64 + (c & 3)];
    sig[r][c] = (P_rc - S_r * S_c * INV_N) * INV_NM1;
    __syncthreads();

    if (tid == 0) {
        float tr = 0.0f;
        for (int i = 0; i < 16; ++i) tr += sig[i][i];
        trace_s = tr;
    }
    __syncthreads();
    const float tr = trace_s;

    sig[r][c] = sig[r][c] / tr;                 // sigma_n
    pm[r][c]  = (r == c) ? 1.0f : 0.0f;
    __syncthreads();

    for (int it = 0; it < 5; ++it) {
        float a = 0.0f;
        for (int k = 0; k < 16; ++k) a += pm[r][k] * pm[k][c];
        t1[r][c] = a;
        __syncthreads();
        float b2 = 0.0f;
        for (int k = 0; k < 16; ++k) b2 += t1[r][k] * pm[k][c];
        t2[r][c] = b2;
        __syncthreads();
        float d = 0.0f;
        for (int k = 0; k < 16; ++k) d += t2[r][k] * sig[k][c];
        const float np = 0.5f * (3.0f * pm[r][c] - d);
        __syncthreads();
        pm[r][c] = np;
        __syncthreads();
    }

    const float inv_sqrt_tr = 1.0f / sqrtf(tr); // W = pm * inv_sqrt_tr
    const float gc = gamma[ci * 16 + c];
    ws[WS_WG + ci * 256 + r * 16 + c] = pm[r][c] * inv_sqrt_tr * gc;
    if (r == 0) {
        float s = 0.0f;
        for (int a = 0; a < 16; ++a) {
            const float mean_a = red2[(a >> 2) * 68 + 64 + (a & 3)] * INV_N;
            s += mean_a * pm[a][c];
        }
        ws[WS_C0 + ci * 16 + c] = beta[ci * 16 + c] - gc * s * inv_sqrt_tr;
    }
}

// ---------------------------------------------------------------------------
// Kernel 3: out = x @ WG + C0 (all normalization constants pre-folded).
// Same quad structure + depth-1 prefetch as k_stats; lane (tid&3) computes
// columns b0..b0+3 -> dense dwordx4 nt-store (64B/quad, 1KB/wave).
// ---------------------------------------------------------------------------
__global__ __launch_bounds__(256) void k_apply(const float* __restrict__ x,
                                               const float* __restrict__ ws,
                                               float* __restrict__ out) {
    const int ci    = blockIdx.x & 31;
    const int chunk = blockIdx.x >> 5;          // 0..31
    const int tid   = threadIdx.x;
    const int sub   = tid & 3;
    const int quad  = tid >> 2;
    const int b0    = sub * 4;

    float wg[16][4];
    const float* WG = ws + WS_WG + ci * 256;
#pragma unroll
    for (int a = 0; a < 16; ++a) {
        const float4 w4 = *reinterpret_cast<const float4*>(WG + a * 16 + b0);
        wg[a][0] = w4.x; wg[a][1] = w4.y; wg[a][2] = w4.z; wg[a][3] = w4.w;
    }
    const float4 c4 = *reinterpret_cast<const float4*>(ws + WS_C0 + ci * 16 + b0);
    const float c0[4] = {c4.x, c4.y, c4.z, c4.w};

    const size_t base =
        (((size_t)(chunk * 64 + (quad >> 5)) * 32 + ci) * 32 + (quad & 31)) * 16;
    const float* p = x + base;
    float* q = out + base + b0;

    auto body = [&](const float4& f0, const float4& f1,
                    const float4& f2, const float4& f3, float* qq) {
        const float v[16] = {f0.x, f0.y, f0.z, f0.w,  f1.x, f1.y, f1.z, f1.w,
                             f2.x, f2.y, f2.z, f2.w,  f3.x, f3.y, f3.z, f3.w};
        float oacc[4] = {c0[0], c0[1], c0[2], c0[3]};
#pragma unroll
        for (int a = 0; a < 16; ++a) {
#pragma unroll
            for (int i = 0; i < 4; ++i) oacc[i] += v[a] * wg[a][i];
        }
        f32x4 o;
        o.x = oacc[0]; o.y = oacc[1]; o.z = oacc[2]; o.w = oacc[3];
        __builtin_nontemporal_store(o, reinterpret_cast<f32x4*>(qq));
    };

    float4 f0 = *reinterpret_cast<const float4*>(p);
    float4 f1 = *reinterpret_cast<const float4*>(p + 4);
    float4 f2 = *reinterpret_cast<const float4*>(p + 8);
    float4 f3 = *reinterpret_cast<const float4*>(p + 12);

    for (int it = 0; it < 31; ++it) {
        const float* pn = p + 32768;
        const float4 g0 = *reinterpret_cast<const float4*>(pn);
        const float4 g1 = *reinterpret_cast<const float4*>(pn + 4);
        const float4 g2 = *reinterpret_cast<const float4*>(pn + 8);
        const float4 g3 = *reinterpret_cast<const float4*>(pn + 12);

        body(f0, f1, f2, f3, q);

        f0 = g0; f1 = g1; f2 = g2; f3 = g3;
        p = pn; q += 32768;
    }
    body(f0, f1, f2, f3, q);                    // peeled last iteration
}

// ---------------------------------------------------------------------------
extern "C" void kernel_launch(void* const* d_in, const int* in_sizes, int n_in,
                              void* d_out, int out_size, void* d_ws, size_t ws_size,
                              hipStream_t stream) {
    const float* x     = (const float*)d_in[0];
    const float* gamma = (const float*)d_in[1];
    const float* beta  = (const float*)d_in[2];
    float* out = (float*)d_out;
    float* ws  = (float*)d_ws;

    k_stats<<<dim3(1024), dim3(256), 0, stream>>>(x, ws);
    k_ns<<<dim3(32), dim3(256), 0, stream>>>(gamma, beta, ws);
    k_apply<<<dim3(1024), dim3(256), 0, stream>>>(x, ws, out);
}

// Round 8
// 92.351 us; speedup vs baseline: 1.6542x; 1.6542x over previous
//
#include <hip/hip_runtime.h>
#include <math.h>

// Problem constants (reference: B=2048, CI=32, CO=32, A=16, ITER_NUM=5)
constexpr int CI = 32;
constexpr int CO = 32;
constexpr float INV_N   = 1.0f / 65536.0f;
constexpr float INV_NM1 = 1.0f / 65535.0f;

constexpr int NCHUNK = 64;                 // stats chunks per capsule
constexpr int PART_STRIDE = 272;           // 16 rows * 17 (16 cols + 1 sum)

// d_ws float layout (no zero-init required):
//   WS_PART: [CI][NCHUNK][272] per-block partials, canonical row*17+col
//   WS_WG:   [CI][16][16]  folded W*gamma
//   WS_C0:   [CI][16]      folded bias: beta - (mean @ W)*gamma
constexpr int WS_PART = 0;
constexpr int WS_WG   = CI * NCHUNK * PART_STRIDE;   // 557056
constexpr int WS_C0   = WS_WG + CI * 256;

using f32x4 = __attribute__((ext_vector_type(4))) float;

// Broadcast float from quad-lane q to all lanes of the quad (VALU DPP).
template <int CTRL>
__device__ __forceinline__ float quad_bcast(float v) {
    return __int_as_float(
        __builtin_amdgcn_mov_dpp(__float_as_int(v), CTRL, 0xf, 0xf, true));
}

// ---------------------------------------------------------------------------
// Kernel 1: per-capsule raw sums S[a] = sum x_a, P[a][b] = sum x_a x_b.
// Grid: 32 ci * 64 chunks = 2048 blocks of 256 threads.
// 8-lane group owns a vector PAIR: lane loads ONE dense 16B quarter (wave =
// one contiguous 1KB dwordx4), gets the partner vector's same quarter via
// shfl_xor(4), rebuilds both full vectors with DPP quad-broadcasts, and
// accumulates a 2x16 slab (rows 4*(s&3)+2*(s>>2)+{0,1}) -> acc = 32 VGPRs,
// no spills (R7 failure), ~5 waves/SIMD for latency hiding.
// ---------------------------------------------------------------------------
__global__ __launch_bounds__(256) void k_stats(const float* __restrict__ x,
                                               float* __restrict__ ws) {
    const int ci    = blockIdx.x & 31;
    const int chunk = blockIdx.x >> 5;          // 0..63
    const int tid   = threadIdx.x;
    const int lane  = tid & 63;
    const int wv    = tid >> 6;
    const int s     = lane & 7;                 // role in 8-lane group
    const int qp    = s & 3;                    // quarter this lane loads
    const int h     = s >> 2;                   // which vec of the pair

    float acc[2][16];
    float sacc[2] = {0.0f, 0.0f};
#pragma unroll
    for (int i = 0; i < 2; ++i)
#pragma unroll
        for (int b2 = 0; b2 < 16; ++b2) acc[i][b2] = 0.0f;

    // n = chunk*1024 + it*64 + wv*16 + (lane>>2); b = n>>5; co = n&31.
    // float idx = (b*1024 + ci*32 + co)*16 + (lane&3)*4  -> dense per wave.
    // it++ -> b += 2 -> constant stride 32768 floats (128 KB).
    const float* p = x +
        (((size_t)(chunk * 32 + (wv >> 1)) * 1024) + ci * 32 +
         (wv & 1) * 16 + (lane >> 2)) * 16 + (lane & 3) * 4;

    for (int it = 0; it < 16; ++it, p += 32768) {
        const float4 f = *reinterpret_cast<const float4*>(p);
        const float fo[4] = {f.x, f.y, f.z, f.w};
        float go[4];
#pragma unroll
        for (int j = 0; j < 4; ++j) go[j] = __shfl_xor(fo[j], 4, 64);

        float vh[16], vo[16];
#pragma unroll
        for (int j = 0; j < 4; ++j) {
            vh[0  + j] = quad_bcast<0x00>(fo[j]);
            vh[4  + j] = quad_bcast<0x55>(fo[j]);
            vh[8  + j] = quad_bcast<0xAA>(fo[j]);
            vh[12 + j] = quad_bcast<0xFF>(fo[j]);
            vo[0  + j] = quad_bcast<0x00>(go[j]);
            vo[4  + j] = quad_bcast<0x55>(go[j]);
            vo[8  + j] = quad_bcast<0xAA>(go[j]);
            vo[12 + j] = quad_bcast<0xFF>(go[j]);
        }

        // own rows = elements 2h, 2h+1 of the lane's own quarter.
        const float owf[2] = {h ? fo[2] : fo[0], h ? fo[3] : fo[1]};
        const float owg[2] = {h ? go[2] : go[0], h ? go[3] : go[1]};

#pragma unroll
        for (int i = 0; i < 2; ++i) {
            sacc[i] += owf[i] + owg[i];
#pragma unroll
            for (int b2 = 0; b2 < 16; ++b2)
                acc[i][b2] += owf[i] * vh[b2] + owg[i] * vo[b2];
        }
    }

    // Butterfly-reduce across the 8 groups of the wave (same role s).
#pragma unroll
    for (int m = 8; m < 64; m <<= 1) {
#pragma unroll
        for (int i = 0; i < 2; ++i) {
            sacc[i] += __shfl_xor(sacc[i], m, 64);
#pragma unroll
            for (int b2 = 0; b2 < 16; ++b2)
                acc[i][b2] += __shfl_xor(acc[i][b2], m, 64);
        }
    }

    // Cross-wave reduce in LDS, canonical layout row*17 + col (+16 = sum).
    __shared__ float red[4][272];
    if (lane < 8) {
#pragma unroll
        for (int i = 0; i < 2; ++i) {
            const int row = 4 * qp + 2 * h + i;
#pragma unroll
            for (int b2 = 0; b2 < 16; ++b2)
                red[wv][row * 17 + b2] = acc[i][b2];
            red[wv][row * 17 + 16] = sacc[i];
        }
    }
    __syncthreads();
    float* slot = ws + WS_PART + (ci * NCHUNK + chunk) * PART_STRIDE;
    for (int e = tid; e < 272; e += 256) {
        slot[e] = red[0][e] + red[1][e] + red[2][e] + red[3][e];
    }
}

// ---------------------------------------------------------------------------
// Kernel 2: reduce chunk partials, Newton-Schulz inverse sqrt, then FOLD the
// epilogue constants: WG = W*gamma (per column), C0 = beta - (mean@W)*gamma.
// 32 blocks (one per ci) of 256 threads.
// ---------------------------------------------------------------------------
__global__ __launch_bounds__(256) void k_ns(const float* __restrict__ gamma,
                                            const float* __restrict__ beta,
                                            float* __restrict__ ws) {
    const int ci  = blockIdx.x;
    const int tid = threadIdx.x;
    const int r = tid >> 4, c = tid & 15;

    __shared__ float red2[272];
    __shared__ float sig[16][17];
    __shared__ float pm[16][17];
    __shared__ float t1[16][17];
    __shared__ float t2[16][17];
    __shared__ float trace_s;

    const float* base = ws + WS_PART + (size_t)ci * NCHUNK * PART_STRIDE;
    for (int e = tid; e < 272; e += 256) {
        float s = 0.0f;
#pragma unroll
        for (int ch = 0; ch < NCHUNK; ++ch)
            s += base[ch * PART_STRIDE + e];
        red2[e] = s;
    }
    __syncthreads();

    // sigma[r][c] = (P_rc - S_r*S_c/N) / (N-1)   (canonical partial layout)
    const float P_rc = red2[r * 17 + c];
    const float S_r  = red2[r * 17 + 16];
    const float S_c  = red2[c * 17 + 16];
    sig[r][c] = (P_rc - S_r * S_c * INV_N) * INV_NM1;
    __syncthreads();

    if (tid == 0) {
        float tr = 0.0f;
        for (int i = 0; i < 16; ++i) tr += sig[i][i];
        trace_s = tr;
    }
    __syncthreads();
    const float tr = trace_s;

    sig[r][c] = sig[r][c] / tr;                 // sigma_n
    pm[r][c]  = (r == c) ? 1.0f : 0.0f;
    __syncthreads();

    for (int it = 0; it < 5; ++it) {
        float a = 0.0f;
        for (int k = 0; k < 16; ++k) a += pm[r][k] * pm[k][c];
        t1[r][c] = a;
        __syncthreads();
        float b2 = 0.0f;
        for (int k = 0; k < 16; ++k) b2 += t1[r][k] * pm[k][c];
        t2[r][c] = b2;
        __syncthreads();
        float d = 0.0f;
        for (int k = 0; k < 16; ++k) d += t2[r][k] * sig[k][c];
        const float np = 0.5f * (3.0f * pm[r][c] - d);
        __syncthreads();
        pm[r][c] = np;
        __syncthreads();
    }

    const float inv_sqrt_tr = 1.0f / sqrtf(tr); // W = pm * inv_sqrt_tr
    const float gc = gamma[ci * 16 + c];
    ws[WS_WG + ci * 256 + r * 16 + c] = pm[r][c] * inv_sqrt_tr * gc;
    if (r == 0) {
        float s = 0.0f;
        for (int a = 0; a < 16; ++a) {
            const float mean_a = red2[a * 17 + 16] * INV_N;
            s += mean_a * pm[a][c];
        }
        ws[WS_C0 + ci * 16 + c] = beta[ci * 16 + c] - gc * s * inv_sqrt_tr;
    }
}

// ---------------------------------------------------------------------------
// Kernel 3: out = x @ WG + C0 (all normalization constants pre-folded).
// UNCHANGED from R7 (measured: ns+apply+gaps = 35.7 us, near write-roofline).
// ---------------------------------------------------------------------------
__global__ __launch_bounds__(256) void k_apply(const float* __restrict__ x,
                                               const float* __restrict__ ws,
                                               float* __restrict__ out) {
    const int ci    = blockIdx.x & 31;
    const int chunk = blockIdx.x >> 5;          // 0..31
    const int tid   = threadIdx.x;
    const int sub   = tid & 3;
    const int quad  = tid >> 2;
    const int b0    = sub * 4;

    float wg[16][4];
    const float* WG = ws + WS_WG + ci * 256;
#pragma unroll
    for (int a = 0; a < 16; ++a) {
        const float4 w4 = *reinterpret_cast<const float4*>(WG + a * 16 + b0);
        wg[a][0] = w4.x; wg[a][1] = w4.y; wg[a][2] = w4.z; wg[a][3] = w4.w;
    }
    const float4 c4 = *reinterpret_cast<const float4*>(ws + WS_C0 + ci * 16 + b0);
    const float c0[4] = {c4.x, c4.y, c4.z, c4.w};

    const size_t base =
        (((size_t)(chunk * 64 + (quad >> 5)) * 32 + ci) * 32 + (quad & 31)) * 16;
    const float* p = x + base;
    float* q = out + base + b0;

    auto body = [&](const float4& f0, const float4& f1,
                    const float4& f2, const float4& f3, float* qq) {
        const float v[16] = {f0.x, f0.y, f0.z, f0.w,  f1.x, f1.y, f1.z, f1.w,
                             f2.x, f2.y, f2.z, f2.w,  f3.x, f3.y, f3.z, f3.w};
        float oacc[4] = {c0[0], c0[1], c0[2], c0[3]};
#pragma unroll
        for (int a = 0; a < 16; ++a) {
#pragma unroll
            for (int i = 0; i < 4; ++i) oacc[i] += v[a] * wg[a][i];
        }
        f32x4 o;
        o.x = oacc[0]; o.y = oacc[1]; o.z = oacc[2]; o.w = oacc[3];
        __builtin_nontemporal_store(o, reinterpret_cast<f32x4*>(qq));
    };

    float4 f0 = *reinterpret_cast<const float4*>(p);
    float4 f1 = *reinterpret_cast<const float4*>(p + 4);
    float4 f2 = *reinterpret_cast<const float4*>(p + 8);
    float4 f3 = *reinterpret_cast<const float4*>(p + 12);

    for (int it = 0; it < 31; ++it) {
        const float* pn = p + 32768;
        const float4 g0 = *reinterpret_cast<const float4*>(pn);
        const float4 g1 = *reinterpret_cast<const float4*>(pn + 4);
        const float4 g2 = *reinterpret_cast<const float4*>(pn + 8);
        const float4 g3 = *reinterpret_cast<const float4*>(pn + 12);

        body(f0, f1, f2, f3, q);

        f0 = g0; f1 = g1; f2 = g2; f3 = g3;
        p = pn; q += 32768;
    }
    body(f0, f1, f2, f3, q);                    // peeled last iteration
}

// ---------------------------------------------------------------------------
extern "C" void kernel_launch(void* const* d_in, const int* in_sizes, int n_in,
                              void* d_out, int out_size, void* d_ws, size_t ws_size,
                              hipStream_t stream) {
    const float* x     = (const float*)d_in[0];
    const float* gamma = (const float*)d_in[1];
    const float* beta  = (const float*)d_in[2];
    float* out = (float*)d_out;
    float* ws  = (float*)d_ws;

    k_stats<<<dim3(2048), dim3(256), 0, stream>>>(x, ws);
    k_ns<<<dim3(32), dim3(256), 0, stream>>>(gamma, beta, ws);
    k_apply<<<dim3(1024), dim3(256), 0, stream>>>(x, ws, out);
}

// Round 9
// 88.954 us; speedup vs baseline: 1.7174x; 1.0382x over previous
//
#include <hip/hip_runtime.h>
#include <math.h>

// Problem constants (reference: B=2048, CI=32, CO=32, A=16, ITER_NUM=5)
constexpr int CI = 32;
constexpr int CO = 32;
constexpr float INV_N   = 1.0f / 65536.0f;
constexpr float INV_NM1 = 1.0f / 65535.0f;

constexpr int NCHUNK = 64;                 // stats chunks per capsule
constexpr int PART_STRIDE = 272;           // 16 rows * 17 (16 cols + 1 sum)

// d_ws float layout (no zero-init required):
//   WS_PART: [CI][NCHUNK][272] per-block partials, canonical row*17+col
//   WS_WG:   [CI][16][16]  folded W*gamma
//   WS_C0:   [CI][16]      folded bias: beta - (mean @ W)*gamma
constexpr int WS_PART = 0;
constexpr int WS_WG   = CI * NCHUNK * PART_STRIDE;   // 557056
constexpr int WS_C0   = WS_WG + CI * 256;

constexpr int STRIDE_IT = 32768;           // floats per stats iteration step

using f32x4 = __attribute__((ext_vector_type(4))) float;

// Broadcast float from quad-lane q to all lanes of the quad (VALU DPP).
template <int CTRL>
__device__ __forceinline__ float quad_bcast(float v) {
    return __int_as_float(
        __builtin_amdgcn_mov_dpp(__float_as_int(v), CTRL, 0xf, 0xf, true));
}

// ---------------------------------------------------------------------------
// Kernel 1: per-capsule raw sums S[a] = sum x_a, P[a][b] = sum x_a x_b.
// Grid: 32 ci * 64 chunks = 2048 blocks of 256 threads.
// 8-lane group owns a vector PAIR; lane loads ONE dense 16B quarter (wave =
// contiguous 1KB per dwordx4), partner quarter via shfl_xor(4), full vectors
// via DPP quad-broadcasts; lane accumulates a 2x16 slab (32 acc VGPRs).
// LATENCY FIX vs R8 (2.4 TB/s): (a) depth-2 ping-pong prefetch keeps 2KB of
// unique bytes in flight during compute; (b) vh-pass then vo-pass halves the
// live DPP-rebuild registers -> ~80 VGPR, ~6 waves/SIMD.
// ---------------------------------------------------------------------------
__global__ __launch_bounds__(256) void k_stats(const float* __restrict__ x,
                                               float* __restrict__ ws) {
    const int ci    = blockIdx.x & 31;
    const int chunk = blockIdx.x >> 5;          // 0..63
    const int tid   = threadIdx.x;
    const int lane  = tid & 63;
    const int wv    = tid >> 6;
    const int s     = lane & 7;                 // role in 8-lane group
    const int qp    = s & 3;                    // quarter this lane loads
    const int h     = s >> 2;                   // which vec of the pair

    float acc[2][16];
    float sacc[2] = {0.0f, 0.0f};
#pragma unroll
    for (int i = 0; i < 2; ++i)
#pragma unroll
        for (int b2 = 0; b2 < 16; ++b2) acc[i][b2] = 0.0f;

    // n = chunk*1024 + it*64 + wv*16 + (lane>>2); b = n>>5; co = n&31.
    // float idx = (b*1024 + ci*32 + co)*16 + (lane&3)*4 -> dense 1KB per wave.
    const float* p = x +
        (((size_t)(chunk * 32 + (wv >> 1)) * 1024) + ci * 32 +
         (wv & 1) * 16 + (lane >> 2)) * 16 + (lane & 3) * 4;

    auto process = [&](const float4& f) {
        const float fo[4] = {f.x, f.y, f.z, f.w};
        float go[4];
#pragma unroll
        for (int j = 0; j < 4; ++j) go[j] = __shfl_xor(fo[j], 4, 64);

        const float owf[2] = {h ? fo[2] : fo[0], h ? fo[3] : fo[1]};
        const float owg[2] = {h ? go[2] : go[0], h ? go[3] : go[1]};

        {   // pass 1: own-half vector (only vh's 16 regs live)
            float vh[16];
#pragma unroll
            for (int j = 0; j < 4; ++j) {
                vh[0  + j] = quad_bcast<0x00>(fo[j]);
                vh[4  + j] = quad_bcast<0x55>(fo[j]);
                vh[8  + j] = quad_bcast<0xAA>(fo[j]);
                vh[12 + j] = quad_bcast<0xFF>(fo[j]);
            }
#pragma unroll
            for (int i = 0; i < 2; ++i) {
                sacc[i] += owf[i];
#pragma unroll
                for (int b2 = 0; b2 < 16; ++b2) acc[i][b2] += owf[i] * vh[b2];
            }
        }
        {   // pass 2: partner vector
            float vo[16];
#pragma unroll
            for (int j = 0; j < 4; ++j) {
                vo[0  + j] = quad_bcast<0x00>(go[j]);
                vo[4  + j] = quad_bcast<0x55>(go[j]);
                vo[8  + j] = quad_bcast<0xAA>(go[j]);
                vo[12 + j] = quad_bcast<0xFF>(go[j]);
            }
#pragma unroll
            for (int i = 0; i < 2; ++i) {
                sacc[i] += owg[i];
#pragma unroll
                for (int b2 = 0; b2 < 16; ++b2) acc[i][b2] += owg[i] * vo[b2];
            }
        }
    };

    // Depth-2 ping-pong: rounds of 2 iterations; next round's 2 dense loads
    // are issued BEFORE this round's ~400cy of DPP/FMA work.
    float4 A0 = *reinterpret_cast<const float4*>(p);
    float4 A1 = *reinterpret_cast<const float4*>(p + STRIDE_IT);
    for (int r = 0; r < 8; ++r) {
        float4 B0, B1;
        if (r < 7) {
            B0 = *reinterpret_cast<const float4*>(p + 2 * STRIDE_IT);
            B1 = *reinterpret_cast<const float4*>(p + 3 * STRIDE_IT);
        }
        process(A0);
        process(A1);
        if (r < 7) { A0 = B0; A1 = B1; p += 2 * STRIDE_IT; }
    }

    // Butterfly-reduce across the 8 groups of the wave (same role s).
#pragma unroll
    for (int m = 8; m < 64; m <<= 1) {
#pragma unroll
        for (int i = 0; i < 2; ++i) {
            sacc[i] += __shfl_xor(sacc[i], m, 64);
#pragma unroll
            for (int b2 = 0; b2 < 16; ++b2)
                acc[i][b2] += __shfl_xor(acc[i][b2], m, 64);
        }
    }

    // Cross-wave reduce in LDS, canonical layout row*17 + col (+16 = sum).
    __shared__ float red[4][272];
    if (lane < 8) {
#pragma unroll
        for (int i = 0; i < 2; ++i) {
            const int row = 4 * qp + 2 * h + i;
#pragma unroll
            for (int b2 = 0; b2 < 16; ++b2)
                red[wv][row * 17 + b2] = acc[i][b2];
            red[wv][row * 17 + 16] = sacc[i];
        }
    }
    __syncthreads();
    float* slot = ws + WS_PART + (ci * NCHUNK + chunk) * PART_STRIDE;
    for (int e = tid; e < 272; e += 256) {
        slot[e] = red[0][e] + red[1][e] + red[2][e] + red[3][e];
    }
}

// ---------------------------------------------------------------------------
// Kernel 2: reduce chunk partials, Newton-Schulz inverse sqrt, then FOLD the
// epilogue constants: WG = W*gamma (per column), C0 = beta - (mean@W)*gamma.
// 32 blocks (one per ci) of 256 threads.
// ---------------------------------------------------------------------------
__global__ __launch_bounds__(256) void k_ns(const float* __restrict__ gamma,
                                            const float* __restrict__ beta,
                                            float* __restrict__ ws) {
    const int ci  = blockIdx.x;
    const int tid = threadIdx.x;
    const int r = tid >> 4, c = tid & 15;

    __shared__ float red2[272];
    __shared__ float sig[16][17];
    __shared__ float pm[16][17];
    __shared__ float t1[16][17];
    __shared__ float t2[16][17];
    __shared__ float trace_s;

    const float* base = ws + WS_PART + (size_t)ci * NCHUNK * PART_STRIDE;
    for (int e = tid; e < 272; e += 256) {
        float s = 0.0f;
#pragma unroll
        for (int ch = 0; ch < NCHUNK; ++ch)
            s += base[ch * PART_STRIDE + e];
        red2[e] = s;
    }
    __syncthreads();

    // sigma[r][c] = (P_rc - S_r*S_c/N) / (N-1)   (canonical partial layout)
    const float P_rc = red2[r * 17 + c];
    const float S_r  = red2[r * 17 + 16];
    const float S_c  = red2[c * 17 + 16];
    sig[r][c] = (P_rc - S_r * S_c * INV_N) * INV_NM1;
    __syncthreads();

    if (tid == 0) {
        float tr = 0.0f;
        for (int i = 0; i < 16; ++i) tr += sig[i][i];
        trace_s = tr;
    }
    __syncthreads();
    const float tr = trace_s;

    sig[r][c] = sig[r][c] / tr;                 // sigma_n
    pm[r][c]  = (r == c) ? 1.0f : 0.0f;
    __syncthreads();

    for (int it = 0; it < 5; ++it) {
        float a = 0.0f;
        for (int k = 0; k < 16; ++k) a += pm[r][k] * pm[k][c];
        t1[r][c] = a;
        __syncthreads();
        float b2 = 0.0f;
        for (int k = 0; k < 16; ++k) b2 += t1[r][k] * pm[k][c];
        t2[r][c] = b2;
        __syncthreads();
        float d = 0.0f;
        for (int k = 0; k < 16; ++k) d += t2[r][k] * sig[k][c];
        const float np = 0.5f * (3.0f * pm[r][c] - d);
        __syncthreads();
        pm[r][c] = np;
        __syncthreads();
    }

    const float inv_sqrt_tr = 1.0f / sqrtf(tr); // W = pm * inv_sqrt_tr
    const float gc = gamma[ci * 16 + c];
    ws[WS_WG + ci * 256 + r * 16 + c] = pm[r][c] * inv_sqrt_tr * gc;
    if (r == 0) {
        float s = 0.0f;
        for (int a = 0; a < 16; ++a) {
            const float mean_a = red2[a * 17 + 16] * INV_N;
            s += mean_a * pm[a][c];
        }
        ws[WS_C0 + ci * 16 + c] = beta[ci * 16 + c] - gc * s * inv_sqrt_tr;
    }
}

// ---------------------------------------------------------------------------
// Kernel 3: out = x @ WG + C0 (all normalization constants pre-folded).
// UNCHANGED (measured R7: ns+apply+gaps = 35.3 us, near write-roofline;
// already has 4 independent loads/iter -> MLP fine).
// ---------------------------------------------------------------------------
__global__ __launch_bounds__(256) void k_apply(const float* __restrict__ x,
                                               const float* __restrict__ ws,
                                               float* __restrict__ out) {
    const int ci    = blockIdx.x & 31;
    const int chunk = blockIdx.x >> 5;          // 0..31
    const int tid   = threadIdx.x;
    const int sub   = tid & 3;
    const int quad  = tid >> 2;
    const int b0    = sub * 4;

    float wg[16][4];
    const float* WG = ws + WS_WG + ci * 256;
#pragma unroll
    for (int a = 0; a < 16; ++a) {
        const float4 w4 = *reinterpret_cast<const float4*>(WG + a * 16 + b0);
        wg[a][0] = w4.x; wg[a][1] = w4.y; wg[a][2] = w4.z; wg[a][3] = w4.w;
    }
    const float4 c4 = *reinterpret_cast<const float4*>(ws + WS_C0 + ci * 16 + b0);
    const float c0[4] = {c4.x, c4.y, c4.z, c4.w};

    const size_t base =
        (((size_t)(chunk * 64 + (quad >> 5)) * 32 + ci) * 32 + (quad & 31)) * 16;
    const float* p = x + base;
    float* q = out + base + b0;

    auto body = [&](const float4& f0, const float4& f1,
                    const float4& f2, const float4& f3, float* qq) {
        const float v[16] = {f0.x, f0.y, f0.z, f0.w,  f1.x, f1.y, f1.z, f1.w,
                             f2.x, f2.y, f2.z, f2.w,  f3.x, f3.y, f3.z, f3.w};
        float oacc[4] = {c0[0], c0[1], c0[2], c0[3]};
#pragma unroll
        for (int a = 0; a < 16; ++a) {
#pragma unroll
            for (int i = 0; i < 4; ++i) oacc[i] += v[a] * wg[a][i];
        }
        f32x4 o;
        o.x = oacc[0]; o.y = oacc[1]; o.z = oacc[2]; o.w = oacc[3];
        __builtin_nontemporal_store(o, reinterpret_cast<f32x4*>(qq));
    };

    float4 f0 = *reinterpret_cast<const float4*>(p);
    float4 f1 = *reinterpret_cast<const float4*>(p + 4);
    float4 f2 = *reinterpret_cast<const float4*>(p + 8);
    float4 f3 = *reinterpret_cast<const float4*>(p + 12);

    for (int it = 0; it < 31; ++it) {
        const float* pn = p + 32768;
        const float4 g0 = *reinterpret_cast<const float4*>(pn);
        const float4 g1 = *reinterpret_cast<const float4*>(pn + 4);
        const float4 g2 = *reinterpret_cast<const float4*>(pn + 8);
        const float4 g3 = *reinterpret_cast<const float4*>(pn + 12);

        body(f0, f1, f2, f3, q);

        f0 = g0; f1 = g1; f2 = g2; f3 = g3;
        p = pn; q += 32768;
    }
    body(f0, f1, f2, f3, q);                    // peeled last iteration
}

// ---------------------------------------------------------------------------
extern "C" void kernel_launch(void* const* d_in, const int* in_sizes, int n_in,
                              void* d_out, int out_size, void* d_ws, size_t ws_size,
                              hipStream_t stream) {
    const float* x     = (const float*)d_in[0];
    const float* gamma = (const float*)d_in[1];
    const float* beta  = (const float*)d_in[2];
    float* out = (float*)d_out;
    float* ws  = (float*)d_ws;

    k_stats<<<dim3(2048), dim3(256), 0, stream>>>(x, ws);
    k_ns<<<dim3(32), dim3(256), 0, stream>>>(gamma, beta, ws);
    k_apply<<<dim3(1024), dim3(256), 0, stream>>>(x, ws, out);
}

// Round 10
// 72.562 us; speedup vs baseline: 2.1054x; 1.2259x over previous
//
#include <hip/hip_runtime.h>
#include <math.h>

// Problem constants (reference: B=2048, CI=32, CO=32, A=16, ITER_NUM=5)
constexpr int CI = 32;
constexpr int CO = 32;
constexpr float INV_N   = 1.0f / 65536.0f;
constexpr float INV_NM1 = 1.0f / 65535.0f;

constexpr int NCHUNK = 32;                 // stats chunks per capsule
constexpr int PART_STRIDE = 272;           // 16 rows * 17 (16 cols + 1 sum)

// d_ws float layout (no zero-init required):
//   WS_PART: [CI][NCHUNK][272] per-block partials, canonical row*17+col
//   WS_WG:   [CI][16][16]  folded W*gamma
//   WS_C0:   [CI][16]      folded bias: beta - (mean @ W)*gamma
constexpr int WS_PART = 0;
constexpr int WS_WG   = CI * NCHUNK * PART_STRIDE;   // 278528
constexpr int WS_C0   = WS_WG + CI * 256;

using f32x4  = __attribute__((ext_vector_type(4))) float;
using bf16x8 = __attribute__((ext_vector_type(8))) short;

// fp32 -> bf16 (round-to-nearest-even), branch-free.
__device__ __forceinline__ unsigned short f2bf(float f) {
    const unsigned int u = __float_as_uint(f);
    return (unsigned short)((u + 0x7FFFu + ((u >> 16) & 1u)) >> 16);
}

// ---------------------------------------------------------------------------
// Kernel 1 (MFMA): per-capsule raw sums S[a] and Gram P[a][b] = sum x_a x_b.
// Grid: 32 ci * 32 chunks = 1024 blocks of 256 threads (4 blocks/CU).
// One mfma_f32_16x16x32_bf16 consumes 32 vectors (one batch's 32 co-slots).
// Gram-matrix trick: A[a][k] = x[k][a] and B[k][b] = x[k][b] have IDENTICAL
// per-lane fragments (A/B layouts are symmetric: row/col = lane&15,
// k = (lane>>4)*8 + reg), so ONE 8-dword load per lane feeds both operands;
// any consistent internal k-permutation cancels in the k-sum, and P is
// symmetric so a row/col transpose would be harmless too.
// S is accumulated in exact fp32 from the same loaded values.
// Replaces R9's ~216 VALU insts per 2KB (shfl/DPP/FMA chains, stall-bound
// at 2.5 TB/s) with ~50 insts + 1 MFMA -> HBM-read-bound.
// ---------------------------------------------------------------------------
__global__ __launch_bounds__(256) void k_stats(const float* __restrict__ x,
                                               float* __restrict__ ws) {
    const int ci    = blockIdx.x & 31;
    const int chunk = blockIdx.x >> 5;          // 0..31
    const int tid   = threadIdx.x;
    const int lane  = tid & 63;
    const int wv    = tid >> 6;
    const int m     = lane & 15;                // row/col index this lane owns
    const int g     = lane >> 4;                // k-group (co = g*8 + j)

    f32x4 acc = {0.0f, 0.0f, 0.0f, 0.0f};
    float sacc = 0.0f;

    // Wave wv handles batches b in [chunk*64 + wv*16, +16), one batch/round.
    // Round r: vector k (= co) = g*8+j of batch b; lane loads x[b][ci][co][m]
    // at float index ((b*32+ci)*32 + g*8+j)*16 + m  -> 8 dwords, stride 64B.
    // Batch stride: 32*32*16 = 16384 floats (64 KB).
    const int b0 = chunk * 64 + wv * 16;
    const float* p = x + ((size_t)(b0 * 32 + ci) * 32 + g * 8) * 16 + m;

    float bufA[8], bufB[8];

    auto ld = [&](float (&d)[8], const float* q) {
#pragma unroll
        for (int j = 0; j < 8; ++j) d[j] = q[j * 16];
    };
    auto step = [&](float (&buf)[8]) {
        union { bf16x8 v; unsigned short h[8]; } fu;
#pragma unroll
        for (int j = 0; j < 8; ++j) {
            sacc += buf[j];                     // exact fp32 column sum
            fu.h[j] = f2bf(buf[j]);
        }
        acc = __builtin_amdgcn_mfma_f32_16x16x32_bf16(fu.v, fu.v, acc, 0, 0, 0);
    };

    // 16 rounds, depth-2 ping-pong prefetch (A/B named buffers, rule #20).
    ld(bufA, p);
    ld(bufB, p + 16384);
    p += 2 * 16384;
#pragma unroll
    for (int rr = 0; rr < 8; ++rr) {
        step(bufA);
        if (rr < 7) { ld(bufA, p); p += 16384; }
        step(bufB);
        if (rr < 7) { ld(bufB, p); p += 16384; }
    }

    // S[m]: sum sacc across the 4 k-groups (lanes 16 apart).
    sacc += __shfl_xor(sacc, 16, 64);
    sacc += __shfl_xor(sacc, 32, 64);

    // C/D layout (m89-verified): lane holds P[row=g*4+q][col=m], q=0..3.
    __shared__ float red[4][272];
#pragma unroll
    for (int q = 0; q < 4; ++q)
        red[wv][(g * 4 + q) * 17 + m] = acc[q];
    if (g == 0) red[wv][m * 17 + 16] = sacc;
    __syncthreads();

    float* slot = ws + WS_PART + (ci * NCHUNK + chunk) * PART_STRIDE;
    for (int e = tid; e < 272; e += 256)
        slot[e] = red[0][e] + red[1][e] + red[2][e] + red[3][e];
}

// ---------------------------------------------------------------------------
// Kernel 2: reduce chunk partials, Newton-Schulz inverse sqrt, then FOLD the
// epilogue constants: WG = W*gamma (per column), C0 = beta - (mean@W)*gamma.
// 32 blocks (one per ci) of 256 threads.
// ---------------------------------------------------------------------------
__global__ __launch_bounds__(256) void k_ns(const float* __restrict__ gamma,
                                            const float* __restrict__ beta,
                                            float* __restrict__ ws) {
    const int ci  = blockIdx.x;
    const int tid = threadIdx.x;
    const int r = tid >> 4, c = tid & 15;

    __shared__ float red2[272];
    __shared__ float sig[16][17];
    __shared__ float pm[16][17];
    __shared__ float t1[16][17];
    __shared__ float t2[16][17];
    __shared__ float trace_s;

    const float* base = ws + WS_PART + (size_t)ci * NCHUNK * PART_STRIDE;
    for (int e = tid; e < 272; e += 256) {
        float s = 0.0f;
#pragma unroll
        for (int ch = 0; ch < NCHUNK; ++ch)
            s += base[ch * PART_STRIDE + e];
        red2[e] = s;
    }
    __syncthreads();

    // sigma[r][c] = (P_rc - S_r*S_c/N) / (N-1)   (canonical partial layout)
    const float P_rc = red2[r * 17 + c];
    const float S_r  = red2[r * 17 + 16];
    const float S_c  = red2[c * 17 + 16];
    sig[r][c] = (P_rc - S_r * S_c * INV_N) * INV_NM1;
    __syncthreads();

    if (tid == 0) {
        float tr = 0.0f;
        for (int i = 0; i < 16; ++i) tr += sig[i][i];
        trace_s = tr;
    }
    __syncthreads();
    const float tr = trace_s;

    sig[r][c] = sig[r][c] / tr;                 // sigma_n
    pm[r][c]  = (r == c) ? 1.0f : 0.0f;
    __syncthreads();

    for (int it = 0; it < 5; ++it) {
        float a = 0.0f;
        for (int k = 0; k < 16; ++k) a += pm[r][k] * pm[k][c];
        t1[r][c] = a;
        __syncthreads();
        float b2 = 0.0f;
        for (int k = 0; k < 16; ++k) b2 += t1[r][k] * pm[k][c];
        t2[r][c] = b2;
        __syncthreads();
        float d = 0.0f;
        for (int k = 0; k < 16; ++k) d += t2[r][k] * sig[k][c];
        const float np = 0.5f * (3.0f * pm[r][c] - d);
        __syncthreads();
        pm[r][c] = np;
        __syncthreads();
    }

    const float inv_sqrt_tr = 1.0f / sqrtf(tr); // W = pm * inv_sqrt_tr
    const float gc = gamma[ci * 16 + c];
    ws[WS_WG + ci * 256 + r * 16 + c] = pm[r][c] * inv_sqrt_tr * gc;
    if (r == 0) {
        float s = 0.0f;
        for (int a = 0; a < 16; ++a) {
            const float mean_a = red2[a * 17 + 16] * INV_N;
            s += mean_a * pm[a][c];
        }
        ws[WS_C0 + ci * 16 + c] = beta[ci * 16 + c] - gc * s * inv_sqrt_tr;
    }
}

// ---------------------------------------------------------------------------
// Kernel 3: out = x @ WG + C0 (all normalization constants pre-folded).
// UNCHANGED (measured R7: ns+apply+gaps ~ 33 us; L3-assisted reads +
// nt-stores; 4 independent loads/iter).
// ---------------------------------------------------------------------------
__global__ __launch_bounds__(256) void k_apply(const float* __restrict__ x,
                                               const float* __restrict__ ws,
                                               float* __restrict__ out) {
    const int ci    = blockIdx.x & 31;
    const int chunk = blockIdx.x >> 5;          // 0..31
    const int tid   = threadIdx.x;
    const int sub   = tid & 3;
    const int quad  = tid >> 2;
    const int b0    = sub * 4;

    float wg[16][4];
    const float* WG = ws + WS_WG + ci * 256;
#pragma unroll
    for (int a = 0; a < 16; ++a) {
        const float4 w4 = *reinterpret_cast<const float4*>(WG + a * 16 + b0);
        wg[a][0] = w4.x; wg[a][1] = w4.y; wg[a][2] = w4.z; wg[a][3] = w4.w;
    }
    const float4 c4 = *reinterpret_cast<const float4*>(ws + WS_C0 + ci * 16 + b0);
    const float c0[4] = {c4.x, c4.y, c4.z, c4.w};

    const size_t base =
        (((size_t)(chunk * 64 + (quad >> 5)) * 32 + ci) * 32 + (quad & 31)) * 16;
    const float* p = x + base;
    float* q = out + base + b0;

    auto body = [&](const float4& f0, const float4& f1,
                    const float4& f2, const float4& f3, float* qq) {
        const float v[16] = {f0.x, f0.y, f0.z, f0.w,  f1.x, f1.y, f1.z, f1.w,
                             f2.x, f2.y, f2.z, f2.w,  f3.x, f3.y, f3.z, f3.w};
        float oacc[4] = {c0[0], c0[1], c0[2], c0[3]};
#pragma unroll
        for (int a = 0; a < 16; ++a) {
#pragma unroll
            for (int i = 0; i < 4; ++i) oacc[i] += v[a] * wg[a][i];
        }
        f32x4 o;
        o.x = oacc[0]; o.y = oacc[1]; o.z = oacc[2]; o.w = oacc[3];
        __builtin_nontemporal_store(o, reinterpret_cast<f32x4*>(qq));
    };

    float4 f0 = *reinterpret_cast<const float4*>(p);
    float4 f1 = *reinterpret_cast<const float4*>(p + 4);
    float4 f2 = *reinterpret_cast<const float4*>(p + 8);
    float4 f3 = *reinterpret_cast<const float4*>(p + 12);

    for (int it = 0; it < 31; ++it) {
        const float* pn = p + 32768;
        const float4 g0 = *reinterpret_cast<const float4*>(pn);
        const float4 g1 = *reinterpret_cast<const float4*>(pn + 4);
        const float4 g2 = *reinterpret_cast<const float4*>(pn + 8);
        const float4 g3 = *reinterpret_cast<const float4*>(pn + 12);

        body(f0, f1, f2, f3, q);

        f0 = g0; f1 = g1; f2 = g2; f3 = g3;
        p = pn; q += 32768;
    }
    body(f0, f1, f2, f3, q);                    // peeled last iteration
}

// ---------------------------------------------------------------------------
extern "C" void kernel_launch(void* const* d_in, const int* in_sizes, int n_in,
                              void* d_out, int out_size, void* d_ws, size_t ws_size,
                              hipStream_t stream) {
    const float* x     = (const float*)d_in[0];
    const float* gamma = (const float*)d_in[1];
    const float* beta  = (const float*)d_in[2];
    float* out = (float*)d_out;
    float* ws  = (float*)d_ws;

    k_stats<<<dim3(1024), dim3(256), 0, stream>>>(x, ws);
    k_ns<<<dim3(32), dim3(256), 0, stream>>>(gamma, beta, ws);
    k_apply<<<dim3(1024), dim3(256), 0, stream>>>(x, ws, out);
}